// Round 6
// baseline (716.273 us; speedup 1.0000x reference)
//
#include <hip/hip_runtime.h>
#include <hip/hip_bf16.h>

// AttributeGNN, bf16 MFMA, fp32 accumulate. B=16384, A=16, D=256.
// R6: weights pre-swizzled into MFMA *fragment order* so every B-load is a
// fully-coalesced 1KB/wave request (R1-R5 had 16-way address-diverged B-loads
// on the MFMA critical path). k1 C-write via LDS bounce; a-split grids.

typedef __bf16 bf16_t;
typedef __bf16 bf16x4 __attribute__((ext_vector_type(4)));
typedef __bf16 bf16x8 __attribute__((ext_vector_type(8)));
typedef float f32x4 __attribute__((ext_vector_type(4)));

#define NB 16384
#define NA 16
#define ND 256

// XOR swizzle for bf16 LDS tiles [32][256]: 8-row stripes spread across 8
// distinct 16B slots; 16-lane column reads -> 2-way (free per m136).
__device__ __forceinline__ int swz(int r, int c) {
    return r * 256 + (c ^ ((r & 7) << 3));
}

// Per-wave 32(M) x 256(K) x 64(N-slice) GEMM. A from swizzled LDS.
// B from global in FRAGMENT layout: fragment f=(nt*8+ks) occupies 512
// consecutive bf16 (64 lanes x 8); lane element = B[nt*16+(lane&15)][ks*32+(lane>>4)*8+m].
// One fragment load = 64 lanes x 16B contiguous = 1KB coalesced.
// C/D layout per m89: col = lane&15, row = (lane>>4)*4 + j.
__device__ __forceinline__ void gemm64(const bf16_t* a_lds, const bf16_t* __restrict__ Bf,
                                       f32x4 acc[2][4], int lane, int wc)
{
    const int lr = lane & 15, lhi = lane >> 4;
    const bf16_t* bp = Bf + wc * 16384 + lane * 8;   // wave's 4 nt-groups
    bf16x8 bq[2][4];
#pragma unroll
    for (int p = 0; p < 2; ++p)
#pragma unroll
        for (int ni = 0; ni < 4; ++ni)
            bq[p][ni] = *(const bf16x8*)&bp[(ni * 8 + p) * 512];
#pragma unroll
    for (int ks = 0; ks < 8; ++ks) {
        const int kc = ks * 32 + lhi * 8;
        bf16x8 af0 = *(const bf16x8*)&a_lds[swz(lr, kc)];
        bf16x8 af1 = *(const bf16x8*)&a_lds[swz(16 + lr, kc)];
#pragma unroll
        for (int ni = 0; ni < 4; ++ni) {
            acc[0][ni] = __builtin_amdgcn_mfma_f32_16x16x32_bf16(af0, bq[ks & 1][ni], acc[0][ni], 0, 0, 0);
            acc[1][ni] = __builtin_amdgcn_mfma_f32_16x16x32_bf16(af1, bq[ks & 1][ni], acc[1][ni], 0, 0, 0);
        }
        if (ks + 2 < 8) {
#pragma unroll
            for (int ni = 0; ni < 4; ++ni)
                bq[ks & 1][ni] = *(const bf16x8*)&bp[(ni * 8 + ks + 2) * 512];
        }
    }
}

// Stage 32 rows x 256 cols fp32 -> swizzled bf16 LDS tile (coalesced 16B/lane).
__device__ __forceinline__ void stage32(const float* __restrict__ base, size_t rstride,
                                        bf16_t* dst, int tid)
{
    const int srr = tid >> 6;          // 0..3
    const int sc4 = (tid & 63) * 4;    // 0..252
#pragma unroll
    for (int h = 0; h < 2; ++h) {
        f32x4 sv[4];
#pragma unroll
        for (int it = 0; it < 4; ++it)
            sv[it] = *(const f32x4*)(base + (size_t)(srr + (h * 4 + it) * 4) * rstride + sc4);
#pragma unroll
        for (int it = 0; it < 4; ++it) {
            int r = srr + (h * 4 + it) * 4;
            bf16x4 s = {(bf16_t)sv[it].x, (bf16_t)sv[it].y, (bf16_t)sv[it].z, (bf16_t)sv[it].w};
            *(bf16x4*)&dst[swz(r, sc4)] = s;
        }
    }
}

// ---- W_agg [256][512] fp32 -> W1f / W2f in fragment layout (bf16).
__global__ void prep_wfrag(const float* __restrict__ W,
                           bf16_t* __restrict__ W1f, bf16_t* __restrict__ W2f)
{
    int t = blockIdx.x * 256 + threadIdx.x;       // 16384 threads
    int lane = t & 63;
    int ks = (t >> 6) & 7;
    int nt = (t >> 9) & 15;
    int half = t >> 13;
    int row = nt * 16 + (lane & 15);
    int col = ks * 32 + (lane >> 4) * 8;
    const float* src = W + (size_t)row * 512 + half * 256 + col;
    bf16_t* dst = (half ? W2f : W1f) + ((nt * 8 + ks) * 64 + lane) * 8;
    bf16x8 v;
#pragma unroll
    for (int m = 0; m < 8; ++m) v[m] = (bf16_t)src[m];
    *(bf16x8*)dst = v;
}

// ---- P[a][i][j] fp32 -> Pt[a][j][i] bf16 (row-major temp) via LDS transpose.
__global__ void transpose_P(const float* __restrict__ Pf, const float* __restrict__ Pb,
                            bf16_t* __restrict__ Pft, bf16_t* __restrict__ Pbt)
{
    __shared__ float t[32][33];
    int blk = blockIdx.x;
    int mat = blk >> 10;
    int rest = blk & 1023;
    int a = rest >> 6;
    int tile = rest & 63;
    int i0 = (tile >> 3) * 32;
    int j0 = (tile & 7) * 32;
    const float* src = (mat ? Pb : Pf) + a * 65536;
    bf16_t* dst = (mat ? Pbt : Pft) + a * 65536;
    int r = threadIdx.x >> 5, c = threadIdx.x & 31;
#pragma unroll
    for (int it = 0; it < 4; ++it)
        t[r + 8 * it][c] = src[(i0 + r + 8 * it) * 256 + j0 + c];
    __syncthreads();
#pragma unroll
    for (int it = 0; it < 4; ++it)
        dst[(j0 + r + 8 * it) * 256 + i0 + c] = (bf16_t)t[c][r + 8 * it];
}

// ---- row-major bf16 [16][256][256] -> fragment layout.
__global__ void prep_pfrag(const bf16_t* __restrict__ Pt, bf16_t* __restrict__ Pfr)
{
    int t = blockIdx.x * 256 + threadIdx.x;       // 131072 threads
    int lane = t & 63;
    int ks = (t >> 6) & 7;
    int nt = (t >> 9) & 15;
    int a = t >> 13;
    bf16x8 v = *(const bf16x8*)&Pt[(size_t)a * 65536 + (nt * 16 + (lane & 15)) * 256 + ks * 32 + (lane >> 4) * 8];
    *(bf16x8*)&Pfr[(size_t)a * 65536 + ((nt * 8 + ks) * 64 + lane) * 8] = v;
}

// ---- K1: T = img@W1^T + bias (regs); per a in [a0,a0+8): agg = T + edge@W2^T
//      -> LDS bounce -> coalesced bf16 ws [a][b][o].
__global__ __launch_bounds__(256, 3)
void k1_agg(const float* __restrict__ img, const float* __restrict__ bias,
            const float* __restrict__ edge,
            const bf16_t* __restrict__ W1f, const bf16_t* __restrict__ W2f,
            bf16_t* __restrict__ aggws)
{
    __shared__ bf16_t E[2][32 * 256];   // 2 x 16 KB edge dbuf
    __shared__ bf16_t O[32 * 256];      // 16 KB C-write bounce

    const int tid = threadIdx.x;
    const int lane = tid & 63;
    const int wc = tid >> 6;
    const int lr = lane & 15;
    const int lhi = lane >> 4;
    const int brow0 = blockIdx.x * 32;
    const int a0 = blockIdx.y * 8;

    stage32(img + (size_t)brow0 * ND, ND, &E[0][0], tid);
    __syncthreads();

    f32x4 T[2][4];
#pragma unroll
    for (int ni = 0; ni < 4; ++ni) {
        float bz = bias[wc * 64 + ni * 16 + lr];
        T[0][ni] = (f32x4){bz, bz, bz, bz};
        T[1][ni] = (f32x4){bz, bz, bz, bz};
    }
    gemm64(&E[0][0], W1f, T, lane, wc);
    __syncthreads();

    stage32(edge + (size_t)brow0 * (NA * ND) + (size_t)a0 * ND, NA * ND, &E[0][0], tid);
    __syncthreads();

    for (int ai = 0; ai < 8; ++ai) {
        const int a = a0 + ai;
        const int cur = ai & 1;
        if (ai + 1 < 8)
            stage32(edge + (size_t)brow0 * (NA * ND) + (size_t)(a + 1) * ND, NA * ND,
                    &E[cur ^ 1][0], tid);
        f32x4 acc[2][4];
#pragma unroll
        for (int mi = 0; mi < 2; ++mi)
#pragma unroll
            for (int ni = 0; ni < 4; ++ni)
                acc[mi][ni] = T[mi][ni];
        gemm64(&E[cur][0], W2f, acc, lane, wc);

        // bounce C fragments through LDS (scattered 2B -> banked LDS, cheap)
#pragma unroll
        for (int mi = 0; mi < 2; ++mi)
#pragma unroll
            for (int ni = 0; ni < 4; ++ni)
#pragma unroll
                for (int j = 0; j < 4; ++j)
                    O[swz(mi * 16 + lhi * 4 + j, wc * 64 + ni * 16 + lr)] = (bf16_t)acc[mi][ni][j];
        __syncthreads();

        // coalesced 16B/lane row stores
        {
            bf16_t* op = aggws + ((size_t)a * NB + brow0) * ND;
            const int r = tid >> 3;
            const int cb = (tid & 7) * 32;
#pragma unroll
            for (int q = 0; q < 4; ++q) {
                bf16x8 v = *(const bf16x8*)&O[swz(r, cb + q * 8)];
                *(bf16x8*)&op[(size_t)r * ND + cb + q * 8] = v;
            }
        }
        __syncthreads();
    }
}

// ---- K2: attr[b,a,:] = agg[a,b,:] @ Pf[a]. One 32-row tile x one a per block.
__global__ __launch_bounds__(256, 4)
void k2_attr(const bf16_t* __restrict__ aggws, const bf16_t* __restrict__ Pff,
             float* __restrict__ out)
{
    __shared__ bf16_t S[32 * 256];

    const int tid = threadIdx.x;
    const int lane = tid & 63;
    const int wc = tid >> 6;
    const int lr = lane & 15;
    const int lhi = lane >> 4;
    const int a = blockIdx.x >> 9;
    const int brow0 = (blockIdx.x & 511) * 32;

    {
        const bf16_t* src = aggws + ((size_t)a * NB + brow0) * ND;
        const int r = tid >> 3;
        const int cb = (tid & 7) * 32;
#pragma unroll
        for (int q = 0; q < 4; ++q) {
            bf16x8 v = *(const bf16x8*)&src[(size_t)r * ND + cb + q * 8];
            *(bf16x8*)&S[swz(r, cb + q * 8)] = v;
        }
    }
    __syncthreads();

    f32x4 acc[2][4];
#pragma unroll
    for (int mi = 0; mi < 2; ++mi)
#pragma unroll
        for (int ni = 0; ni < 4; ++ni)
            acc[mi][ni] = (f32x4){0.f, 0.f, 0.f, 0.f};
    gemm64(&S[0], Pff + (size_t)a * 65536, acc, lane, wc);

    float* op = out + ((size_t)brow0 * NA + a) * ND;
#pragma unroll
    for (int mi = 0; mi < 2; ++mi)
#pragma unroll
        for (int ni = 0; ni < 4; ++ni)
#pragma unroll
            for (int j = 0; j < 4; ++j) {
                int r = mi * 16 + lhi * 4 + j;
                int c = wc * 64 + ni * 16 + lr;
                op[(size_t)r * (NA * ND) + c] = acc[mi][ni][j];
            }
}

// ---- K3: indiv partial over a in [a0,a0+8): sum relu(attr@Pb[a])*sw[a].
__global__ __launch_bounds__(256, 3)
void k3_indiv(const float* attr, const bf16_t* __restrict__ Pbf,
              const float* __restrict__ sw, float* __restrict__ out,
              float* __restrict__ part)
{
    __shared__ bf16_t S[2][32 * 256];

    const int tid = threadIdx.x;
    const int lane = tid & 63;
    const int wc = tid >> 6;
    const int lr = lane & 15;
    const int lhi = lane >> 4;
    const int brow0 = blockIdx.x * 32;
    const int a0 = blockIdx.y * 8;

    stage32(attr + (size_t)brow0 * (NA * ND) + (size_t)a0 * ND, NA * ND, &S[0][0], tid);
    __syncthreads();

    f32x4 indiv[2][4];
#pragma unroll
    for (int mi = 0; mi < 2; ++mi)
#pragma unroll
        for (int ni = 0; ni < 4; ++ni)
            indiv[mi][ni] = (f32x4){0.f, 0.f, 0.f, 0.f};

    for (int ai = 0; ai < 8; ++ai) {
        const int a = a0 + ai;
        const int cur = ai & 1;
        if (ai + 1 < 8)
            stage32(attr + (size_t)brow0 * (NA * ND) + (size_t)(a + 1) * ND, NA * ND,
                    &S[cur ^ 1][0], tid);
        f32x4 acc[2][4];
#pragma unroll
        for (int mi = 0; mi < 2; ++mi)
#pragma unroll
            for (int ni = 0; ni < 4; ++ni)
                acc[mi][ni] = (f32x4){0.f, 0.f, 0.f, 0.f};
        gemm64(&S[cur][0], Pbf + (size_t)a * 65536, acc, lane, wc);
        const float swa = sw[a];
#pragma unroll
        for (int mi = 0; mi < 2; ++mi)
#pragma unroll
            for (int ni = 0; ni < 4; ++ni)
#pragma unroll
                for (int j = 0; j < 4; ++j)
                    indiv[mi][ni][j] += fmaxf(acc[mi][ni][j], 0.f) * swa;
        __syncthreads();
    }

    float* ind = (blockIdx.y == 0) ? out : part;
#pragma unroll
    for (int mi = 0; mi < 2; ++mi)
#pragma unroll
        for (int ni = 0; ni < 4; ++ni)
#pragma unroll
            for (int j = 0; j < 4; ++j) {
                int r = mi * 16 + lhi * 4 + j;
                int c = wc * 64 + ni * 16 + lr;
                ind[(size_t)(brow0 + r) * ND + c] = indiv[mi][ni][j];
            }
}

__global__ void reduce_indiv(float* __restrict__ outI, const float* __restrict__ part)
{
    size_t i = ((size_t)blockIdx.x * 256 + threadIdx.x) * 4;
    f32x4 a = *(const f32x4*)&outI[i];
    f32x4 b = *(const f32x4*)&part[i];
    a.x += b.x; a.y += b.y; a.z += b.z; a.w += b.w;
    *(f32x4*)&outI[i] = a;
}

extern "C" void kernel_launch(void* const* d_in, const int* in_sizes, int n_in,
                              void* d_out, int out_size, void* d_ws, size_t ws_size,
                              hipStream_t stream)
{
    const float* img  = (const float*)d_in[0];
    const float* edge = (const float*)d_in[1];
    const float* Wagg = (const float*)d_in[2];
    const float* bagg = (const float*)d_in[3];
    const float* Pf   = (const float*)d_in[4];
    const float* Pb   = (const float*)d_in[5];
    const float* sw   = (const float*)d_in[6];
    float* out = (float*)d_out;

    char* ws = (char*)d_ws;
    bf16_t* W1f = (bf16_t*)(ws);                   // 128 KB  fragment layout
    bf16_t* W2f = (bf16_t*)(ws + 131072);          // 128 KB
    bf16_t* Pff = (bf16_t*)(ws + 262144);          // 2 MB
    bf16_t* Pbf = (bf16_t*)(ws + 2359296);         // 2 MB
    bf16_t* agg = (bf16_t*)(ws + 4456448);         // 134.2 MB [a][b][o] bf16
    // temps + part alias the agg region (stream-ordered: temps read before k1
    // writes agg; part written by k3 after k2, agg's last reader)
    bf16_t* Ptf  = (bf16_t*)(ws + 4456448);        // 2 MB row-major temp
    bf16_t* Ptb  = (bf16_t*)(ws + 6553600);        // 2 MB row-major temp
    float*  part = (float*)(ws + 4456448);         // 16 MB indiv partial

    prep_wfrag<<<64, 256, 0, stream>>>(Wagg, W1f, W2f);
    transpose_P<<<2048, 256, 0, stream>>>(Pf, Pb, Ptf, Ptb);
    prep_pfrag<<<512, 256, 0, stream>>>(Ptf, Pff);
    prep_pfrag<<<512, 256, 0, stream>>>(Ptb, Pbf);
    k1_agg<<<dim3(NB / 32, 2), 256, 0, stream>>>(img, bagg, edge, W1f, W2f, agg);
    k2_attr<<<NA * (NB / 32), 256, 0, stream>>>(agg, Pff, out);
    k3_indiv<<<dim3(NB / 32, 2), 256, 0, stream>>>(out, Pbf, sw,
                                                   out + (size_t)NB * NA * ND, part);
    reduce_indiv<<<4096, 256, 0, stream>>>(out + (size_t)NB * NA * ND, part);
}